// Round 6
// baseline (595924.512 us; speedup 1.0000x reference)
//
#include <hip/hip_runtime.h>
#include <math.h>

// ControlledNODE: sequential RK4 scan, T=65536 steps.
// Round-6: 2 waves (128 threads), W1/W2 register-resident as in round 4
// (333k us), but only TWO barriers per RK stage instead of four:
//  * L3 computed redundantly per wave: lane (m, kh) holds a half-K W3
//    slice w3r[64]; one intra-wave shfl_xor(32) combines halves -> every
//    wave owns the full drift, no cross-wave pbuf reduce (B3 gone).
//  * RK combine replicated in ALL lanes; each wave writes the identical
//    xbuf[m] and reads back its OWN in-order DS writes next stage; the
//    other wave's identical writes are a benign race (B4 gone).
// Barriers are raw lgkmcnt(0)+s_barrier (no vmcnt drain: U-prefetch and
// out-stores stay in flight across them). 8 barriers/step vs 16.

constexpr int T_STEPS = 65536;
constexpr int HD  = 32;   // state dim
constexpr int HID = 128;  // hidden dim

__device__ __forceinline__ float silu_f(float a) {
    // a * sigmoid(a); exp overflow -> inf -> a/inf = 0 (correct limit)
    return a / (1.0f + __expf(-a));
}

// Workgroup barrier without vmcnt drain.
__device__ __forceinline__ void wg_barrier() {
    asm volatile("s_waitcnt lgkmcnt(0)" ::: "memory");
    __builtin_amdgcn_s_barrier();
    asm volatile("" ::: "memory");
}

__global__ __launch_bounds__(128, 1)
void node_scan(const float* __restrict__ U,
               const float* __restrict__ h0,
               const float* __restrict__ W1, const float* __restrict__ b1,
               const float* __restrict__ W2, const float* __restrict__ b2,
               const float* __restrict__ W3, const float* __restrict__ b3,
               const float* __restrict__ Wd, const float* __restrict__ bd,
               const float* __restrict__ Wt, const float* __restrict__ bt,
               const float* __restrict__ Wc, const float* __restrict__ bc,
               float* __restrict__ out)
{
    const int tid = threadIdx.x;    // 0..127
    const int j   = tid;            // hidden unit owned in L1/L2
    const int wl  = tid & 63;       // lane within wave
    const int m   = wl & 31;        // state/drift index
    const int kh  = wl >> 5;        // 0/1: L3 K-half within this wave
    const int wv  = tid >> 6;       // wave id 0/1

    __shared__ __align__(16) float xbuf[HD];     // RK-stage state input
    __shared__ __align__(16) float z1buf[HID];
    __shared__ __align__(16) float z2buf[HID];

    // ---- one-time: weights into registers (all constant-indexed) ----
    float w1r[40];
#pragma unroll
    for (int i = 0; i < 40; ++i) w1r[i] = W1[i * HID + j];
    const float b1r = b1[j];

    float w2r[HID];
#pragma unroll
    for (int i = 0; i < HID; ++i) w2r[i] = W2[i * HID + j];
    const float b2r = b2[j];

    // L3 half-K slice: drift[m] partial over z2[kh*64 .. kh*64+63]
    float w3r[64];
#pragma unroll
    for (int i = 0; i < 64; ++i) w3r[i] = W3[(kh * 64 + i) * HD + m];
    const float b3r = b3[m];

    // heads: wave0 reduces d and c, wave1 reduces t
    const float whr = (wv == 0) ? Wd[m] : Wt[m];
    const float wcr = Wc[m];
    const float bd0 = bd[0], bt0 = bt[0], bc0 = bc[0];

    float hm   = h0[m];    // replicated in all 128 lanes
    float xm   = hm;       // current stage input state x[m]
    float kacc = 0.0f;

    const float DT  = 5.0f / 60.0f;
    const float HDT = 0.5f * DT;
    const float W6  = DT / 6.0f;

    // u double-buffer (same addr all lanes -> broadcast, L2-cached)
    float4 ua = *(const float4*)(U);
    float4 ub = *(const float4*)(U + 4);

    xbuf[m] = xm;                    // every wave writes its own full copy
    __builtin_amdgcn_wave_barrier();

    for (int t = 0; t < T_STEPS; ++t) {
        // prefetch next step's u (no vmcnt drain at barriers -> stays in flight)
        const int tn = (t + 1 < T_STEPS) ? (t + 1) : t;
        const float4 na = *(const float4*)(U + tn * 8);
        const float4 nb = *(const float4*)(U + tn * 8 + 4);

        // ---- heads from current h (pre-update): pure reg + shuffle ----
        // hm duplicated across each 32-lane half -> 5-step reduce, no mask
        {
            float p  = hm * whr;
            float pc = hm * wcr;
            p += __shfl_xor(p, 16);  pc += __shfl_xor(pc, 16);
            p += __shfl_xor(p, 8);   pc += __shfl_xor(pc, 8);
            p += __shfl_xor(p, 4);   pc += __shfl_xor(pc, 4);
            p += __shfl_xor(p, 2);   pc += __shfl_xor(pc, 2);
            p += __shfl_xor(p, 1);   pc += __shfl_xor(pc, 1);
            if (tid == 0)  { out[t] = p + bd0; out[2 * T_STEPS + t] = pc + bc0; }
            if (tid == 64) { out[T_STEPS + t] = p + bt0; }
        }

        // ---- u-projection: constant across the 4 RK stages, hoisted ----
        float upj = b1r;
        upj = fmaf(ua.x, w1r[32], upj);
        upj = fmaf(ua.y, w1r[33], upj);
        upj = fmaf(ua.z, w1r[34], upj);
        upj = fmaf(ua.w, w1r[35], upj);
        upj = fmaf(ub.x, w1r[36], upj);
        upj = fmaf(ub.y, w1r[37], upj);
        upj = fmaf(ub.z, w1r[38], upj);
        upj = fmaf(ub.w, w1r[39], upj);

#pragma unroll
        for (int st = 0; st < 4; ++st) {
            // ---- L1: z1[j] = silu([x,u] @ W1 + b1) ----
            // xbuf read hits this wave's OWN in-order writes: no barrier.
            float a0 = upj, a1 = 0.0f, a2 = 0.0f, a3 = 0.0f;
            const float4* xv = (const float4*)xbuf;
#pragma unroll
            for (int i4 = 0; i4 < 8; ++i4) {
                const float4 v = xv[i4];            // broadcast read
                a0 = fmaf(v.x, w1r[4 * i4 + 0], a0);
                a1 = fmaf(v.y, w1r[4 * i4 + 1], a1);
                a2 = fmaf(v.z, w1r[4 * i4 + 2], a2);
                a3 = fmaf(v.w, w1r[4 * i4 + 3], a3);
            }
            z1buf[j] = silu_f((a0 + a1) + (a2 + a3));
            wg_barrier();                            // B1: z1 cross-wave

            // ---- L2: z2[j] = silu(z1 @ W2 + b2), W2 in registers ----
            float c0 = b2r, c1 = 0.0f, c2 = 0.0f, c3 = 0.0f;
            const float4* z1v = (const float4*)z1buf;
#pragma unroll
            for (int i4 = 0; i4 < 32; ++i4) {
                const float4 v = z1v[i4];           // broadcast read
                c0 = fmaf(v.x, w2r[4 * i4 + 0], c0);
                c1 = fmaf(v.y, w2r[4 * i4 + 1], c1);
                c2 = fmaf(v.z, w2r[4 * i4 + 2], c2);
                c3 = fmaf(v.w, w2r[4 * i4 + 3], c3);
            }
            z2buf[j] = silu_f((c0 + c1) + (c2 + c3));
            wg_barrier();                            // B2: z2 cross-wave

            // ---- L3: drift[m] over K-half kh, redundant per wave ----
            float p0 = 0.0f, p1 = 0.0f, p2 = 0.0f, p3 = 0.0f;
            const float4* z2v = (const float4*)(z2buf + kh * 64);
#pragma unroll
            for (int i4 = 0; i4 < 16; ++i4) {
                const float4 v = z2v[i4];           // 2 addr groups: free
                p0 = fmaf(v.x, w3r[4 * i4 + 0], p0);
                p1 = fmaf(v.y, w3r[4 * i4 + 1], p1);
                p2 = fmaf(v.z, w3r[4 * i4 + 2], p2);
                p3 = fmaf(v.w, w3r[4 * i4 + 3], p3);
            }
            float drift = (p0 + p1) + (p2 + p3);
            drift += __shfl_xor(drift, 32);         // combine halves in-wave
            drift += b3r;

            // ---- RK combine: ALL lanes redundantly (drift replicated) ----
            const float k = 0.02f * drift - 0.1f * xm;
            if (st == 0)      { kacc = k;           xm = hm + HDT * k; }
            else if (st == 1) { kacc += 2.0f * k;   xm = hm + HDT * k; }
            else if (st == 2) { kacc += 2.0f * k;   xm = hm + DT  * k; }
            else {
                kacc += k;
                float hn = hm + W6 * kacc;
                if (!isfinite(hn)) hn = 0.0f;        // nan_to_num BEFORE tanh
                hn = tanhf(hn);
                hn = fminf(fmaxf(hn, -5.0f), 5.0f);  // fidelity no-op after tanh
                hm = hn; xm = hn;
            }
            xbuf[m] = xm;   // identical value from every writer: benign race
            __builtin_amdgcn_wave_barrier();
        }
        ua = na; ub = nb;
    }

    if (tid < HD) out[3 * T_STEPS + tid] = hm;
}

extern "C" void kernel_launch(void* const* d_in, const int* in_sizes, int n_in,
                              void* d_out, int out_size, void* d_ws, size_t ws_size,
                              hipStream_t stream) {
    const float* U  = (const float*)d_in[0];
    const float* h0 = (const float*)d_in[1];
    const float* W1 = (const float*)d_in[2];
    const float* b1 = (const float*)d_in[3];
    const float* W2 = (const float*)d_in[4];
    const float* b2 = (const float*)d_in[5];
    const float* W3 = (const float*)d_in[6];
    const float* b3 = (const float*)d_in[7];
    const float* Wd = (const float*)d_in[8];
    const float* bd = (const float*)d_in[9];
    const float* Wt = (const float*)d_in[10];
    const float* bt = (const float*)d_in[11];
    const float* Wc = (const float*)d_in[12];
    const float* bc = (const float*)d_in[13];
    float* out = (float*)d_out;

    node_scan<<<1, 128, 0, stream>>>(U, h0, W1, b1, W2, b2, W3, b3,
                                     Wd, bd, Wt, bt, Wc, bc, out);
}

// Round 7
// 292235.132 us; speedup vs baseline: 2.0392x; 2.0392x over previous
//
#include <hip/hip_runtime.h>
#include <math.h>

// ControlledNODE: sequential RK4 scan, T=65536 steps.
// Round-7: round-4 structure (2 waves, 200 weight floats/lane -> VGPR 136,
// AGPR parking OK) with barrier analysis applied:
//   B1 (z1 -> L2)  : crosses waves -> FULL barrier
//   B2 (z2 -> L3)  : wave-local   -> free wave_barrier (seg>>5 maps each
//                    wave's L3 reads onto its own z2 writes)
//   B3 (pbuf reduce): crosses waves -> FULL barrier
//   B4 (xbuf -> L1): wave-local    -> free wave_barrier (ALL lanes write
//                    identical xbuf[m]; each wave reads its own writes)
// => 8 full barriers/step instead of 16, at round-4's register budget.
// Full barriers are raw lgkmcnt(0)+s_barrier (no vmcnt drain).

constexpr int T_STEPS = 65536;
constexpr int HD  = 32;   // state dim
constexpr int HID = 128;  // hidden dim

__device__ __forceinline__ float silu_f(float a) {
    // a * sigmoid(a); exp overflow -> inf -> a/inf = 0 (correct limit)
    return a / (1.0f + __expf(-a));
}

// Workgroup barrier without vmcnt drain.
__device__ __forceinline__ void wg_barrier() {
    asm volatile("s_waitcnt lgkmcnt(0)" ::: "memory");
    __builtin_amdgcn_s_barrier();
    asm volatile("" ::: "memory");
}

__global__ __launch_bounds__(128, 1)
void node_scan(const float* __restrict__ U,
               const float* __restrict__ h0,
               const float* __restrict__ W1, const float* __restrict__ b1,
               const float* __restrict__ W2, const float* __restrict__ b2,
               const float* __restrict__ W3, const float* __restrict__ b3,
               const float* __restrict__ Wd, const float* __restrict__ bd,
               const float* __restrict__ Wt, const float* __restrict__ bt,
               const float* __restrict__ Wc, const float* __restrict__ bc,
               float* __restrict__ out)
{
    const int tid = threadIdx.x;    // 0..127
    const int j   = tid;            // hidden unit owned (L1/L2)
    const int m   = tid & 31;       // state/drift index
    const int seg = tid >> 5;       // L3 K-segment 0..3 (wave-local: 0,1 | 2,3)
    const int wv  = tid >> 6;       // wave id 0/1

    __shared__ __align__(16) float xbuf[HD];     // RK-stage state input
    __shared__ __align__(16) float z1buf[HID];
    __shared__ __align__(16) float z2buf[HID];
    __shared__ __align__(16) float pbuf[HID];    // L3 partials

    // ---- one-time: weights into registers (all constant-indexed) ----
    float w1r[40];
#pragma unroll
    for (int i = 0; i < 40; ++i) w1r[i] = W1[i * HID + j];
    const float b1r = b1[j];

    float w2r[HID];
#pragma unroll
    for (int i = 0; i < HID; ++i) w2r[i] = W2[i * HID + j];
    const float b2r = b2[j];

    float w3r[32];
#pragma unroll
    for (int i = 0; i < 32; ++i) w3r[i] = W3[(seg * 32 + i) * HD + m];
    const float b3r = b3[m];

    // heads: wave0 reduces d and c, wave1 reduces t
    const float whr = (wv == 0) ? Wd[m] : Wt[m];
    const float wcr = Wc[m];
    const float bd0 = bd[0], bt0 = bt[0], bc0 = bc[0];

    float hm   = h0[m];    // replicated in all 128 lanes
    float xm   = hm;       // current stage input state x[m]
    float kacc = 0.0f;

    const float DT  = 5.0f / 60.0f;
    const float HDT = 0.5f * DT;
    const float W6  = DT / 6.0f;

    // u double-buffer (same addr all lanes -> broadcast, L2-cached)
    float4 ua = *(const float4*)(U);
    float4 ub = *(const float4*)(U + 4);

    xbuf[m] = xm;                    // all lanes, identical values: benign
    wg_barrier();

    for (int t = 0; t < T_STEPS; ++t) {
        // prefetch next step's u (no vmcnt drain at barriers -> in flight)
        const int tn = (t + 1 < T_STEPS) ? (t + 1) : t;
        const float4 na = *(const float4*)(U + tn * 8);
        const float4 nb = *(const float4*)(U + tn * 8 + 4);

        // ---- heads from current h (pre-update): pure reg + shuffle ----
        // hm replicated across each 32-lane half -> 5-step reduce, no mask
        {
            float p  = hm * whr;
            float pc = hm * wcr;
            p += __shfl_xor(p, 16);  pc += __shfl_xor(pc, 16);
            p += __shfl_xor(p, 8);   pc += __shfl_xor(pc, 8);
            p += __shfl_xor(p, 4);   pc += __shfl_xor(pc, 4);
            p += __shfl_xor(p, 2);   pc += __shfl_xor(pc, 2);
            p += __shfl_xor(p, 1);   pc += __shfl_xor(pc, 1);
            if (tid == 0)  { out[t] = p + bd0; out[2 * T_STEPS + t] = pc + bc0; }
            if (tid == 64) { out[T_STEPS + t] = p + bt0; }
        }

        // ---- u-projection: constant across the 4 RK stages, hoisted ----
        float upj = b1r;
        upj = fmaf(ua.x, w1r[32], upj);
        upj = fmaf(ua.y, w1r[33], upj);
        upj = fmaf(ua.z, w1r[34], upj);
        upj = fmaf(ua.w, w1r[35], upj);
        upj = fmaf(ub.x, w1r[36], upj);
        upj = fmaf(ub.y, w1r[37], upj);
        upj = fmaf(ub.z, w1r[38], upj);
        upj = fmaf(ub.w, w1r[39], upj);

#pragma unroll
        for (int st = 0; st < 4; ++st) {
            // ---- L1: z1[j] = silu([x,u] @ W1 + b1) ----
            // xbuf read hits this wave's OWN in-order writes.
            float a0 = upj, a1 = 0.0f, a2 = 0.0f, a3 = 0.0f;
            const float4* xv = (const float4*)xbuf;
#pragma unroll
            for (int i4 = 0; i4 < 8; ++i4) {
                const float4 v = xv[i4];            // broadcast read
                a0 = fmaf(v.x, w1r[4 * i4 + 0], a0);
                a1 = fmaf(v.y, w1r[4 * i4 + 1], a1);
                a2 = fmaf(v.z, w1r[4 * i4 + 2], a2);
                a3 = fmaf(v.w, w1r[4 * i4 + 3], a3);
            }
            z1buf[j] = silu_f((a0 + a1) + (a2 + a3));
            wg_barrier();                            // B1: z1 crosses waves

            // ---- L2: z2[j] = silu(z1 @ W2 + b2), W2 in registers ----
            float c0 = b2r, c1 = 0.0f, c2 = 0.0f, c3 = 0.0f;
            const float4* z1v = (const float4*)z1buf;
#pragma unroll
            for (int i4 = 0; i4 < 32; ++i4) {
                const float4 v = z1v[i4];           // broadcast read
                c0 = fmaf(v.x, w2r[4 * i4 + 0], c0);
                c1 = fmaf(v.y, w2r[4 * i4 + 1], c1);
                c2 = fmaf(v.z, w2r[4 * i4 + 2], c2);
                c3 = fmaf(v.w, w2r[4 * i4 + 3], c3);
            }
            z2buf[j] = silu_f((c0 + c1) + (c2 + c3));
            __builtin_amdgcn_wave_barrier();         // B2: wave-local (see hdr)

            // ---- L3 partial: drift[m] over segment seg (own wave's z2) ----
            float p0 = 0.0f, p1 = 0.0f, p2 = 0.0f, p3 = 0.0f;
            const float4* z2v = (const float4*)(z2buf + seg * 32);
#pragma unroll
            for (int i4 = 0; i4 < 8; ++i4) {
                const float4 v = z2v[i4];           // 2 addr groups: free
                p0 = fmaf(v.x, w3r[4 * i4 + 0], p0);
                p1 = fmaf(v.y, w3r[4 * i4 + 1], p1);
                p2 = fmaf(v.z, w3r[4 * i4 + 2], p2);
                p3 = fmaf(v.w, w3r[4 * i4 + 3], p3);
            }
            pbuf[tid] = (p0 + p1) + (p2 + p3);
            wg_barrier();                            // B3: pbuf crosses waves

            // ---- RK combine: ALL lanes redundantly (hm replicated) ----
            {
                const float drift = ((pbuf[m] + pbuf[m + 32]) +
                                     (pbuf[m + 64] + pbuf[m + 96])) + b3r;
                const float k = 0.02f * drift - 0.1f * xm;
                if (st == 0)      { kacc = k;           xm = hm + HDT * k; }
                else if (st == 1) { kacc += 2.0f * k;   xm = hm + HDT * k; }
                else if (st == 2) { kacc += 2.0f * k;   xm = hm + DT  * k; }
                else {
                    kacc += k;
                    float hn = hm + W6 * kacc;
                    if (!isfinite(hn)) hn = 0.0f;        // nan_to_num BEFORE tanh
                    hn = tanhf(hn);
                    hn = fminf(fmaxf(hn, -5.0f), 5.0f);  // fidelity no-op after tanh
                    hm = hn; xm = hn;
                }
                xbuf[m] = xm;   // all lanes, identical values: benign race
            }
            __builtin_amdgcn_wave_barrier();         // B4: wave-local
        }
        ua = na; ub = nb;
    }

    if (tid < HD) out[3 * T_STEPS + tid] = hm;
}

extern "C" void kernel_launch(void* const* d_in, const int* in_sizes, int n_in,
                              void* d_out, int out_size, void* d_ws, size_t ws_size,
                              hipStream_t stream) {
    const float* U  = (const float*)d_in[0];
    const float* h0 = (const float*)d_in[1];
    const float* W1 = (const float*)d_in[2];
    const float* b1 = (const float*)d_in[3];
    const float* W2 = (const float*)d_in[4];
    const float* b2 = (const float*)d_in[5];
    const float* W3 = (const float*)d_in[6];
    const float* b3 = (const float*)d_in[7];
    const float* Wd = (const float*)d_in[8];
    const float* bd = (const float*)d_in[9];
    const float* Wt = (const float*)d_in[10];
    const float* bt = (const float*)d_in[11];
    const float* Wc = (const float*)d_in[12];
    const float* bc = (const float*)d_in[13];
    float* out = (float*)d_out;

    node_scan<<<1, 128, 0, stream>>>(U, h0, W1, b1, W2, b2, W3, b3,
                                     Wd, bd, Wt, bt, Wc, bc, out);
}

// Round 8
// 237476.270 us; speedup vs baseline: 2.5094x; 1.2306x over previous
//
#include <hip/hip_runtime.h>
#include <math.h>

// ControlledNODE: sequential RK4 scan, T=65536 steps.
// Round-8 = round-7 (2 waves, 2 s_barriers/stage, W1/W2/W3 register-resident,
// VGPR 124) + two changes:
//  * Packed FP32: all matvec FMAs as 2-wide vector fma -> v_pk_fma_f32
//    (CDNA4 VOP3P), halving VALU issue slots (L2: 128 -> 64 instrs).
//    Generated via __builtin_elementwise_fma on ext_vector_type(2):
//    safe (scalarizes correctly if backend declines).
//  * Shallow L3 reduce: seg-pair partials combined pre-barrier with one
//    intra-wave shfl_xor(32); pbuf 128 -> 64 entries; post-B3 chain is
//    read2+add instead of read4+3 adds.
// Barrier map (validated round 7): B1 (z1, cross-wave), B3 (pb2,
// cross-wave) are full lgkmcnt+s_barrier; z2->L3 and xbuf->L1 are
// wave-local (in-order DS within a wave; identical-value races benign).

constexpr int T_STEPS = 65536;
constexpr int HD  = 32;   // state dim
constexpr int HID = 128;  // hidden dim

typedef float v2f __attribute__((ext_vector_type(2)));

__device__ __forceinline__ v2f fma2(v2f a, v2f b, v2f c) {
    return __builtin_elementwise_fma(a, b, c);   // -> v_pk_fma_f32
}

__device__ __forceinline__ float silu_f(float a) {
    // a * sigmoid(a); exp overflow -> inf -> a/inf = 0 (correct limit)
    return a / (1.0f + __expf(-a));
}

// Workgroup barrier without vmcnt drain.
__device__ __forceinline__ void wg_barrier() {
    asm volatile("s_waitcnt lgkmcnt(0)" ::: "memory");
    __builtin_amdgcn_s_barrier();
    asm volatile("" ::: "memory");
}

__global__ __launch_bounds__(128, 1)
void node_scan(const float* __restrict__ U,
               const float* __restrict__ h0,
               const float* __restrict__ W1, const float* __restrict__ b1,
               const float* __restrict__ W2, const float* __restrict__ b2,
               const float* __restrict__ W3, const float* __restrict__ b3,
               const float* __restrict__ Wd, const float* __restrict__ bd,
               const float* __restrict__ Wt, const float* __restrict__ bt,
               const float* __restrict__ Wc, const float* __restrict__ bc,
               float* __restrict__ out)
{
    const int tid = threadIdx.x;    // 0..127
    const int j   = tid;            // hidden unit owned (L1/L2)
    const int m   = tid & 31;       // state/drift index
    const int seg = tid >> 5;       // L3 K-segment 0..3 (wave-local pairs)
    const int wv  = tid >> 6;       // wave id 0/1

    __shared__ __align__(16) float xbuf[HD];     // RK-stage state input
    __shared__ __align__(16) float z1buf[HID];
    __shared__ __align__(16) float z2buf[HID];
    __shared__ __align__(16) float pb2[64];      // per-wave K-half drift partials

    // ---- one-time: weights into registers as packed pairs ----
    v2f w1p[20];                                  // [0..15]=x part, [16..19]=u part
#pragma unroll
    for (int i = 0; i < 20; ++i) {
        w1p[i].x = W1[(2 * i) * HID + j];
        w1p[i].y = W1[(2 * i + 1) * HID + j];
    }
    const float b1r = b1[j];

    v2f w2p[64];
#pragma unroll
    for (int i = 0; i < 64; ++i) {
        w2p[i].x = W2[(2 * i) * HID + j];
        w2p[i].y = W2[(2 * i + 1) * HID + j];
    }
    const float b2r = b2[j];

    v2f w3p[16];                                  // seg slice, packed pairs
#pragma unroll
    for (int i = 0; i < 16; ++i) {
        w3p[i].x = W3[(seg * 32 + 2 * i) * HD + m];
        w3p[i].y = W3[(seg * 32 + 2 * i + 1) * HD + m];
    }
    const float b3r = b3[m];

    // heads: wave0 reduces d and c, wave1 reduces t
    const float whr = (wv == 0) ? Wd[m] : Wt[m];
    const float wcr = Wc[m];
    const float bd0 = bd[0], bt0 = bt[0], bc0 = bc[0];

    float hm   = h0[m];    // replicated in all 128 lanes
    float xm   = hm;       // current stage input state x[m]
    float kacc = 0.0f;

    const float DT  = 5.0f / 60.0f;
    const float HDT = 0.5f * DT;
    const float W6  = DT / 6.0f;

    // u double-buffer (same addr all lanes -> broadcast, L2-cached)
    float4 ua = *(const float4*)(U);
    float4 ub = *(const float4*)(U + 4);

    xbuf[m] = xm;                    // all lanes, identical values: benign
    wg_barrier();

    for (int t = 0; t < T_STEPS; ++t) {
        // prefetch next step's u (no vmcnt drain at barriers -> in flight)
        const int tn = (t + 1 < T_STEPS) ? (t + 1) : t;
        const float4 na = *(const float4*)(U + tn * 8);
        const float4 nb = *(const float4*)(U + tn * 8 + 4);

        // ---- heads from current h (pre-update): pure reg + shuffle ----
        {
            float p  = hm * whr;
            float pc = hm * wcr;
            p += __shfl_xor(p, 16);  pc += __shfl_xor(pc, 16);
            p += __shfl_xor(p, 8);   pc += __shfl_xor(pc, 8);
            p += __shfl_xor(p, 4);   pc += __shfl_xor(pc, 4);
            p += __shfl_xor(p, 2);   pc += __shfl_xor(pc, 2);
            p += __shfl_xor(p, 1);   pc += __shfl_xor(pc, 1);
            if (tid == 0)  { out[t] = p + bd0; out[2 * T_STEPS + t] = pc + bc0; }
            if (tid == 64) { out[T_STEPS + t] = p + bt0; }
        }

        // ---- u-projection: constant across the 4 RK stages, hoisted ----
        float upj;
        {
            v2f u0; u0.x = ua.x; u0.y = ua.y;
            v2f u1; u1.x = ua.z; u1.y = ua.w;
            v2f u2; u2.x = ub.x; u2.y = ub.y;
            v2f u3; u3.x = ub.z; u3.y = ub.w;
            v2f up = {b1r, 0.0f};
            up = fma2(u0, w1p[16], up);
            up = fma2(u1, w1p[17], up);
            up = fma2(u2, w1p[18], up);
            up = fma2(u3, w1p[19], up);
            upj = up.x + up.y;
        }

#pragma unroll
        for (int st = 0; st < 4; ++st) {
            // ---- L1: z1[j] = silu([x,u] @ W1 + b1), packed ----
            v2f a0 = {upj, 0.0f}, a1 = {0.0f, 0.0f};
            const float4* xv = (const float4*)xbuf;
#pragma unroll
            for (int i4 = 0; i4 < 8; ++i4) {
                const float4 v = xv[i4];            // broadcast read
                v2f lo; lo.x = v.x; lo.y = v.y;
                v2f hi; hi.x = v.z; hi.y = v.w;
                a0 = fma2(lo, w1p[2 * i4],     a0);
                a1 = fma2(hi, w1p[2 * i4 + 1], a1);
            }
            const v2f as = a0 + a1;
            z1buf[j] = silu_f(as.x + as.y);
            wg_barrier();                            // B1: z1 crosses waves

            // ---- L2: z2[j] = silu(z1 @ W2 + b2), packed, W2 in regs ----
            v2f c0 = {b2r, 0.0f}, c1 = {0.0f, 0.0f};
            v2f c2 = {0.0f, 0.0f}, c3 = {0.0f, 0.0f};
            const float4* z1v = (const float4*)z1buf;
#pragma unroll
            for (int i4 = 0; i4 < 32; ++i4) {
                const float4 v = z1v[i4];           // broadcast read
                v2f lo; lo.x = v.x; lo.y = v.y;
                v2f hi; hi.x = v.z; hi.y = v.w;
                if (i4 & 1) {
                    c2 = fma2(lo, w2p[2 * i4],     c2);
                    c3 = fma2(hi, w2p[2 * i4 + 1], c3);
                } else {
                    c0 = fma2(lo, w2p[2 * i4],     c0);
                    c1 = fma2(hi, w2p[2 * i4 + 1], c1);
                }
            }
            const v2f cs = (c0 + c1) + (c2 + c3);
            z2buf[j] = silu_f(cs.x + cs.y);
            __builtin_amdgcn_wave_barrier();         // wave-local: z2 -> L3

            // ---- L3 partial: drift[m] over segment seg (own wave's z2) ----
            v2f p0 = {0.0f, 0.0f}, p1 = {0.0f, 0.0f};
            const float4* z2v = (const float4*)(z2buf + seg * 32);
#pragma unroll
            for (int i4 = 0; i4 < 8; ++i4) {
                const float4 v = z2v[i4];           // 2 addr groups: free
                v2f lo; lo.x = v.x; lo.y = v.y;
                v2f hi; hi.x = v.z; hi.y = v.w;
                p0 = fma2(lo, w3p[2 * i4],     p0);
                p1 = fma2(hi, w3p[2 * i4 + 1], p1);
            }
            const v2f ps = p0 + p1;
            float pr = ps.x + ps.y;
            pr += __shfl_xor(pr, 32);   // combine seg pair within wave
            // wave0 holds k<64 partial, wave1 holds k>=64 partial (all lanes)
            pb2[wv * 32 + m] = pr;      // 2 lanes/addr, same value: benign
            wg_barrier();                            // B3: pb2 crosses waves

            // ---- RK combine: ALL lanes redundantly (hm replicated) ----
            {
                const float drift = (pb2[m] + pb2[m + 32]) + b3r;
                const float k = 0.02f * drift - 0.1f * xm;
                if (st == 0)      { kacc = k;           xm = hm + HDT * k; }
                else if (st == 1) { kacc += 2.0f * k;   xm = hm + HDT * k; }
                else if (st == 2) { kacc += 2.0f * k;   xm = hm + DT  * k; }
                else {
                    kacc += k;
                    float hn = hm + W6 * kacc;
                    if (!isfinite(hn)) hn = 0.0f;        // nan_to_num BEFORE tanh
                    hn = tanhf(hn);
                    hn = fminf(fmaxf(hn, -5.0f), 5.0f);  // fidelity no-op after tanh
                    hm = hn; xm = hn;
                }
                xbuf[m] = xm;   // all lanes, identical values: benign race
            }
            __builtin_amdgcn_wave_barrier();         // wave-local: xbuf -> L1
        }
        ua = na; ub = nb;
    }

    if (tid < HD) out[3 * T_STEPS + tid] = hm;
}

extern "C" void kernel_launch(void* const* d_in, const int* in_sizes, int n_in,
                              void* d_out, int out_size, void* d_ws, size_t ws_size,
                              hipStream_t stream) {
    const float* U  = (const float*)d_in[0];
    const float* h0 = (const float*)d_in[1];
    const float* W1 = (const float*)d_in[2];
    const float* b1 = (const float*)d_in[3];
    const float* W2 = (const float*)d_in[4];
    const float* b2 = (const float*)d_in[5];
    const float* W3 = (const float*)d_in[6];
    const float* b3 = (const float*)d_in[7];
    const float* Wd = (const float*)d_in[8];
    const float* bd = (const float*)d_in[9];
    const float* Wt = (const float*)d_in[10];
    const float* bt = (const float*)d_in[11];
    const float* Wc = (const float*)d_in[12];
    const float* bc = (const float*)d_in[13];
    float* out = (float*)d_out;

    node_scan<<<1, 128, 0, stream>>>(U, h0, W1, b1, W2, b2, W3, b3,
                                     Wd, bd, Wt, bt, Wc, bc, out);
}